// Round 13
// baseline (112.603 us; speedup 1.0000x reference)
//
#include <hip/hip_runtime.h>
#include <math.h>

#define EPSV 1e-12f

namespace {
constexpr int N_  = 4;
constexpr int C_  = 128;
constexpr int H_  = 30;
constexpr int W_  = 40;
constexpr int K_  = 64;
constexpr int HW_ = H_ * W_;        // 1200
constexpr int HP_ = 27;             // H+1-4
constexpr int WP_ = 37;             // W+1-4
constexpr int P_  = HP_ * WP_;      // 999
constexpr int PS_ = 1000;           // padded stride for p-indexed buffers
constexpr int KC_ = K_ * C_;        // 8192
constexpr int CP_ = C_ * P_;        // 127872 floats per (n,k) slab
constexpr int CS_ = HP_ * W_;       // 1080 colsum rows
constexpr int SL_ = CS_ / 4;        // 270 vector slots
constexpr int CVP_ = 132;           // padded row stride for conv_s / xrowT
constexpr int WH_ = 20;             // w-half width for K1
}

static __device__ __forceinline__ float4 ld4(const float* p) {
    return *reinterpret_cast<const float4*>(p);
}
static __device__ __forceinline__ float dot4(float4 a, float4 b) {
    return a.x * b.x + a.y * b.y + a.z * b.z + a.w * b.w;
}
static __device__ __forceinline__ float4 f4add(float4 a, float4 b) {
    return make_float4(a.x + b.x, a.y + b.y, a.z + b.z, a.w + b.w);
}
static __device__ __forceinline__ float4 f4mul(float4 a, float4 b) {
    return make_float4(a.x * b.x, a.y * b.y, a.z * b.z, a.w * b.w);
}

// ---------------------------------------------------------------------------
// K1: per (n,h,w-half) — 240 blocks. L2-normalize x over channels, write xn
//     in two layouts, conv scores + softmax. (verified, unchanged)
// ---------------------------------------------------------------------------
__global__ __launch_bounds__(256) void k1_norm_softmax(
    const float* __restrict__ x, const float* __restrict__ conv_w,
    float* __restrict__ xnT, float* __restrict__ xnP, float* __restrict__ sa)
{
    __shared__ float xrow[C_ * WH_];      // [c][20]
    __shared__ float conv_s[K_ * CVP_];   // [k][132]
    __shared__ float xrowT[WH_ * CVP_];   // [w][132]
    __shared__ float invn[WH_];
    __shared__ float s_s[K_ * WH_];       // [k][20]

    const int b  = blockIdx.x;            // (n*H + h)*2 + wh
    const int wh = b & 1;
    const int nh = b >> 1;
    const int n = nh / H_, h = nh - n * H_;
    const int wbase = wh * WH_;
    const int t = threadIdx.x;

    for (int i = t; i < C_ * WH_; i += 256) {
        const int c = i / WH_, w = i - c * WH_;
        xrow[i] = x[(size_t)(n * C_ + c) * HW_ + h * W_ + wbase + w];
    }
    for (int i = t; i < K_ * C_; i += 256) {
        const int k = i >> 7, c = i & 127;
        conv_s[k * CVP_ + c] = conv_w[i];
    }
    __syncthreads();

    if (t < 8 * WH_) {
        const int w = t >> 3, g = t & 7;
        float s = 0.f;
#pragma unroll
        for (int i = 0; i < 16; ++i) {
            const float v = xrow[(g + 8 * i) * WH_ + w];
            s += v * v;
        }
        s += __shfl_xor(s, 1);
        s += __shfl_xor(s, 2);
        s += __shfl_xor(s, 4);
        if (g == 0) invn[w] = 1.f / fmaxf(sqrtf(s), EPSV);
    }
    __syncthreads();

    for (int i = t; i < C_ * WH_; i += 256) {
        const int c = i / WH_, w = i - c * WH_;
        const float v = xrow[i] * invn[w];
        xrow[i] = v;
        xnT[(size_t)(n * C_ + c) * HW_ + h * W_ + wbase + w] = v;
    }
    __syncthreads();

    for (int i = t; i < WH_ * C_; i += 256) {
        const int w = i >> 7, c = i & 127;
        const float v = xrow[c * WH_ + w];
        xnP[((size_t)n * HW_ + h * W_ + wbase + w) * C_ + c] = v;
        xrowT[w * CVP_ + c] = v;
    }
    __syncthreads();

    {
        const int k = t >> 2, wq = t & 3;
        float acc[5] = {};
        const float* convk = &conv_s[k * CVP_];
        for (int ch = 0; ch < 4; ++ch) {
            float4 cv0 = ld4(convk + ch * 32 + 0),  cv1 = ld4(convk + ch * 32 + 4);
            float4 cv2 = ld4(convk + ch * 32 + 8),  cv3 = ld4(convk + ch * 32 + 12);
            float4 cv4 = ld4(convk + ch * 32 + 16), cv5 = ld4(convk + ch * 32 + 20);
            float4 cv6 = ld4(convk + ch * 32 + 24), cv7 = ld4(convk + ch * 32 + 28);
#pragma unroll
            for (int j = 0; j < 5; ++j) {
                const float* xw = &xrowT[(wq * 5 + j) * CVP_ + ch * 32];
                acc[j] += dot4(cv0, ld4(xw)) + dot4(cv1, ld4(xw + 4))
                        + dot4(cv2, ld4(xw + 8)) + dot4(cv3, ld4(xw + 12))
                        + dot4(cv4, ld4(xw + 16)) + dot4(cv5, ld4(xw + 20))
                        + dot4(cv6, ld4(xw + 24)) + dot4(cv7, ld4(xw + 28));
            }
        }
        float* sd = &s_s[k * WH_ + wq * 5];
#pragma unroll
        for (int j = 0; j < 5; ++j) sd[j] = acc[j];
    }
    __syncthreads();

    if (t < 8 * WH_) {
        const int w = t >> 3, g = t & 7;
        float sv[8];
#pragma unroll
        for (int kk = 0; kk < 8; ++kk) sv[kk] = s_s[(g + 8 * kk) * WH_ + w];
        float m = fmaxf(fmaxf(fmaxf(sv[0], sv[1]), fmaxf(sv[2], sv[3])),
                        fmaxf(fmaxf(sv[4], sv[5]), fmaxf(sv[6], sv[7])));
        m = fmaxf(m, __shfl_xor(m, 1));
        m = fmaxf(m, __shfl_xor(m, 2));
        m = fmaxf(m, __shfl_xor(m, 4));
        float ex[8];
        float sum = 0.f;
#pragma unroll
        for (int kk = 0; kk < 8; ++kk) { ex[kk] = expf(sv[kk] - m); sum += ex[kk]; }
        sum += __shfl_xor(sum, 1);
        sum += __shfl_xor(sum, 2);
        sum += __shfl_xor(sum, 4);
        const float inv = 1.f / sum;
#pragma unroll
        for (int kk = 0; kk < 8; ++kk)
            sa[(size_t)(n * K_ + g + 8 * kk) * HW_ + h * W_ + wbase + w] = ex[kk] * inv;
    }
}

// ---------------------------------------------------------------------------
// Strip colsum (verified, unchanged).
// ---------------------------------------------------------------------------
#define COLSUM_STRIP(cs_q, sa_s, xb, cA_base)                                   \
    if (t < 140) {                                                              \
        const int q2 = t / 70, item = t - q2 * 70;                              \
        const int hq = item / 10, wq = item - hq * 10;                          \
        const int h0 = 4 * hq;                                                  \
        const int nh = (hq < 6) ? 4 : 3;                                        \
        const int cA = (cA_base) + q2 * 16;                                     \
        const float* xp0 = xb + (size_t)(cA + 0)  * HW_ + h0 * W_ + 4 * wq;     \
        const float* xp1 = xb + (size_t)(cA + 4)  * HW_ + h0 * W_ + 4 * wq;     \
        const float* xp2 = xb + (size_t)(cA + 8)  * HW_ + h0 * W_ + 4 * wq;     \
        const float* xp3 = xb + (size_t)(cA + 12) * HW_ + h0 * W_ + 4 * wq;     \
        const float* sap = &sa_s[h0 * W_ + 4 * wq];                             \
        float4 p0[7], p1[7], p2[7], p3[7];                                      \
        _Pragma("unroll")                                                       \
        for (int r = 0; r < 7; ++r) {                                           \
            const float4 sv = ld4(sap + r * W_);                                \
            p0[r] = f4mul(sv, ld4(xp0 + r * W_));                               \
            p1[r] = f4mul(sv, ld4(xp1 + r * W_));                               \
            p2[r] = f4mul(sv, ld4(xp2 + r * W_));                               \
            p3[r] = f4mul(sv, ld4(xp3 + r * W_));                               \
        }                                                                       \
        _Pragma("unroll")                                                       \
        for (int hh = 0; hh < 4; ++hh) {                                        \
            if (hh < nh) {                                                      \
                const float4 c0v = f4add(f4add(p0[hh], p0[hh+1]), f4add(p0[hh+2], p0[hh+3])); \
                const float4 c1v = f4add(f4add(p1[hh], p1[hh+1]), f4add(p1[hh+2], p1[hh+3])); \
                const float4 c2v = f4add(f4add(p2[hh], p2[hh+1]), f4add(p2[hh+2], p2[hh+3])); \
                const float4 c3v = f4add(f4add(p3[hh], p3[hh+1]), f4add(p3[hh+2], p3[hh+3])); \
                const int s = 10 * (h0 + hh) + wq;                              \
                cs_q[q2][0][s] = make_float4(c0v.x, c1v.x, c2v.x, c3v.x);       \
                cs_q[q2][1][s] = make_float4(c0v.y, c1v.y, c2v.y, c3v.y);       \
                cs_q[q2][2][s] = make_float4(c0v.z, c1v.z, c2v.z, c3v.z);       \
                cs_q[q2][3][s] = make_float4(c0v.w, c1v.w, c2v.w, c3v.w);       \
            }                                                                   \
        }                                                                       \
    }

// 10-value window read over one quad array csq[4][SL_+1]. (verified)
#define WINDOW10(csq, b0, d, A0, A1, A2, A3)                                    \
    {                                                                           \
        float4 v0 = csq[(b0 + 0) & 3][(b0 + 0) >> 2];                           \
        float4 v1 = csq[(b0 + 1) & 3][(b0 + 1) >> 2];                           \
        float4 v2 = csq[(b0 + 2) & 3][(b0 + 2) >> 2];                           \
        float4 v3 = csq[(b0 + 3) & 3][(b0 + 3) >> 2];                           \
        float4 v4 = csq[(b0 + 4) & 3][(b0 + 4) >> 2];                           \
        float4 v5 = csq[(b0 + 5) & 3][(b0 + 5) >> 2];                           \
        float4 v6 = csq[(b0 + 6) & 3][(b0 + 6) >> 2];                           \
        float4 v7 = csq[(b0 + 7) & 3][(b0 + 7) >> 2];                           \
        float4 v8 = csq[(b0 + 8) & 3][(b0 + 8) >> 2];                           \
        float4 v9 = csq[(b0 + 9) & 3][(b0 + 9) >> 2];                           \
        const float4 t0 = f4add(v0, v1), t1 = f4add(v1, v2), t2 = f4add(v2, v3);\
        const float4 t3 = f4add(v3, v4), t4 = f4add(v4, v5), t5 = f4add(v5, v6);\
        const float4 t6 = f4add(v6, v7), t7 = f4add(v7, v8), t8 = f4add(v8, v9);\
        const float4 w0 = f4add(t0, t2), w1 = f4add(t1, t3), w2 = f4add(t2, t4);\
        const float4 w3 = f4add(t3, t5), w4 = f4add(t4, t6), w5 = f4add(t5, t7);\
        const float4 w6 = f4add(t6, t8);                                        \
        A0 = (0 < d) ? w0 : w3;                                                 \
        A1 = (1 < d) ? w1 : w4;                                                 \
        A2 = (2 < d) ? w2 : w5;                                                 \
        A3 = (3 < d) ? w3 : w6;                                                 \
    }

// ---------------------------------------------------------------------------
// K4m: merged launch (verified, unchanged).
// ---------------------------------------------------------------------------
__global__ __launch_bounds__(256) void k4_merged(
    const float* __restrict__ sa, const float* __restrict__ xnT,
    const float* __restrict__ xnP, const float* __restrict__ cent,
    float* __restrict__ nsqp, float* __restrict__ vg_u,
    float* __restrict__ vg_r)
{
    __shared__ float  sa_s[1248];         // 31 rows + pad (strip/window overreads)
    __shared__ float4 cs_q[2][4][SL_ + 1];
    __shared__ float  gs[256], bss[256];
    __shared__ float  red[2];

    const int t = threadIdx.x;

    if (blockIdx.x < 256) {
        const int b = blockIdx.x;         // n*K + k
        const int n = b >> 6, k = b & 63;
        const int c = t & 127, half = t >> 7;
        constexpr int HHW = HW_ / 2;      // 600

        const float* sarow = &sa[(size_t)b * HW_ + half * HHW];
        const float* xp = &xnP[((size_t)n * HW_ + half * HHW) * C_ + c];
        float g0 = 0.f, g1 = 0.f, g2 = 0.f, g3 = 0.f;
        float b0 = 0.f, b1 = 0.f, b2 = 0.f, b3 = 0.f;
        for (int pix = 0; pix < HHW; pix += 4) {
            const float s0 = sarow[pix + 0], s1 = sarow[pix + 1];
            const float s2 = sarow[pix + 2], s3 = sarow[pix + 3];
            g0 += s0 * xp[(size_t)(pix + 0) * C_];
            g1 += s1 * xp[(size_t)(pix + 1) * C_];
            g2 += s2 * xp[(size_t)(pix + 2) * C_];
            g3 += s3 * xp[(size_t)(pix + 3) * C_];
            b0 += s0; b1 += s1; b2 += s2; b3 += s3;
        }
        gs[t]  = (g0 + g1) + (g2 + g3);
        bss[t] = (b0 + b1) + (b2 + b3);
        __syncthreads();

        float vg = 0.f;
        if (t < 128) {
            vg = (gs[t] + gs[t + 128]) - cent[k * C_ + c] * (bss[t] + bss[t + 128]);
            float nsq = vg * vg;
            for (int off = 32; off >= 1; off >>= 1) nsq += __shfl_down(nsq, off);
            if ((t & 63) == 0) red[t >> 6] = nsq;
        }
        __syncthreads();
        const float tot  = red[0] + red[1];
        const float norm = sqrtf(tot);
        const float iv   = 1.f / fmaxf(norm, EPSV);
        if (t < 128) vg_u[(size_t)b * C_ + t] = vg * iv;
        if (t == 0) { const float rr = norm * iv; vg_r[b] = rr * rr; }
        return;
    }

    const int b  = blockIdx.x - 256;      // ((n*K + k)*4 + cq)
    const int cq = b & 3;
    const int nk = b >> 2;
    const int n  = nk >> 6, k = nk & 63;

    for (int i = t; i < HW_; i += 256) sa_s[i] = sa[(size_t)nk * HW_ + i];
    __syncthreads();

    // sa box-sum windows (B) in registers (thread t<250 owns p0 = 4t..4t+3)
    int b0 = 0, d = 4;
    float Bw0 = 0.f, Bw1 = 0.f, Bw2 = 0.f, Bw3 = 0.f;
    if (t < 250) {
        const int p0 = 4 * t;
        const int hp0 = p0 / WP_;
        const int wp0 = p0 - hp0 * WP_;
        b0 = p0 + 3 * hp0;
        d  = WP_ - wp0;
        const float* r0 = &sa_s[hp0 * W_ + wp0];
        float sc[10];
#pragma unroll
        for (int j = 0; j < 10; ++j)
            sc[j] = r0[j] + r0[j + W_] + r0[j + 2 * W_] + r0[j + 3 * W_];
        const float u0 = sc[0] + sc[1], u1 = sc[1] + sc[2], u2 = sc[2] + sc[3];
        const float u3 = sc[3] + sc[4], u4 = sc[4] + sc[5], u5 = sc[5] + sc[6];
        const float u6 = sc[6] + sc[7], u7 = sc[7] + sc[8], u8 = sc[8] + sc[9];
        const float wB0 = u0 + u2, wB1 = u1 + u3, wB2 = u2 + u4;
        const float wB3 = u3 + u5, wB4 = u4 + u6, wB5 = u5 + u7, wB6 = u6 + u8;
        Bw0 = (0 < d) ? wB0 : wB3;
        Bw1 = (1 < d) ? wB1 : wB4;
        Bw2 = (2 < d) ? wB2 : wB5;
        Bw3 = (3 < d) ? wB3 : wB6;
    }

    float nsq0 = 0.f, nsq1 = 0.f, nsq2 = 0.f, nsq3 = 0.f;
    const float* xb = xnT + (size_t)n * C_ * HW_;

    for (int iter = 0; iter < 4; ++iter) {
        const int c0 = cq * 32 + iter;    // 8 channels: c0 + 4j, j=0..7
        __syncthreads();                  // prior iteration's cs_q readers done
        COLSUM_STRIP(cs_q, sa_s, xb, c0)
        __syncthreads();
        if (t < 250) {
            const float* ck = &cent[k * C_ + c0];
            const float4 ceA = make_float4(ck[0], ck[4], ck[8], ck[12]);
            const float4 ceB = make_float4(ck[16], ck[20], ck[24], ck[28]);
            float4 A0, A1, A2, A3, Q0, Q1, Q2, Q3;
            WINDOW10(cs_q[0], b0, d, A0, A1, A2, A3)
            WINDOW10(cs_q[1], b0, d, Q0, Q1, Q2, Q3)
            {
                const float4 e = make_float4(A0.x - ceA.x * Bw0, A0.y - ceA.y * Bw0,
                                             A0.z - ceA.z * Bw0, A0.w - ceA.w * Bw0);
                const float4 f = make_float4(Q0.x - ceB.x * Bw0, Q0.y - ceB.y * Bw0,
                                             Q0.z - ceB.z * Bw0, Q0.w - ceB.w * Bw0);
                nsq0 += dot4(e, e) + dot4(f, f);
            }
            {
                const float4 e = make_float4(A1.x - ceA.x * Bw1, A1.y - ceA.y * Bw1,
                                             A1.z - ceA.z * Bw1, A1.w - ceA.w * Bw1);
                const float4 f = make_float4(Q1.x - ceB.x * Bw1, Q1.y - ceB.y * Bw1,
                                             Q1.z - ceB.z * Bw1, Q1.w - ceB.w * Bw1);
                nsq1 += dot4(e, e) + dot4(f, f);
            }
            {
                const float4 e = make_float4(A2.x - ceA.x * Bw2, A2.y - ceA.y * Bw2,
                                             A2.z - ceA.z * Bw2, A2.w - ceA.w * Bw2);
                const float4 f = make_float4(Q2.x - ceB.x * Bw2, Q2.y - ceB.y * Bw2,
                                             Q2.z - ceB.z * Bw2, Q2.w - ceB.w * Bw2);
                nsq2 += dot4(e, e) + dot4(f, f);
            }
            {
                const float4 e = make_float4(A3.x - ceA.x * Bw3, A3.y - ceA.y * Bw3,
                                             A3.z - ceA.z * Bw3, A3.w - ceA.w * Bw3);
                const float4 f = make_float4(Q3.x - ceB.x * Bw3, Q3.y - ceB.y * Bw3,
                                             Q3.z - ceB.z * Bw3, Q3.w - ceB.w * Bw3);
                nsq3 += dot4(e, e) + dot4(f, f);
            }
        }
    }
    if (t < 250) {
        *reinterpret_cast<float4*>(&nsqp[(size_t)b * PS_ + 4 * t]) =
            make_float4(nsq0 * 0.00390625f, nsq1 * 0.00390625f,
                        nsq2 * 0.00390625f, nsq3 * 0.00390625f);
    }
}

// ---------------------------------------------------------------------------
// K5m: blocks[0,256): combine cq partials; [256,260): vg fin. (unchanged)
// ---------------------------------------------------------------------------
__global__ __launch_bounds__(256) void k5_merged(
    const float* __restrict__ nsqp, float* __restrict__ inv1,
    float* __restrict__ rloc, const float* __restrict__ vg_u,
    const float* __restrict__ vg_r, float* __restrict__ out)
{
    const int t = threadIdx.x;
    if (blockIdx.x >= 256) {
        const int n = blockIdx.x - 256;
        __shared__ float inv2s;
        if (t == 0) {
            float s = 0.f;
            for (int k = 0; k < K_; ++k) s += vg_r[n * K_ + k];
            inv2s = 1.f / fmaxf(sqrtf(s), EPSV);
        }
        __syncthreads();
        const float inv2 = inv2s;
        for (int i = t; i < KC_; i += 256)
            out[(size_t)n * KC_ + i] = vg_u[(size_t)n * KC_ + i] * inv2;
        return;
    }
    const int nk = blockIdx.x;
    if (t < 250) {
        const int p0 = 4 * t;
        const float4 a = ld4(&nsqp[(size_t)(nk * 4 + 0) * PS_ + p0]);
        const float4 b = ld4(&nsqp[(size_t)(nk * 4 + 1) * PS_ + p0]);
        const float4 c = ld4(&nsqp[(size_t)(nk * 4 + 2) * PS_ + p0]);
        const float4 e = ld4(&nsqp[(size_t)(nk * 4 + 3) * PS_ + p0]);
        float4 iv, rr;
#pragma unroll
        for (int j = 0; j < 4; ++j) {
            const float s = reinterpret_cast<const float*>(&a)[j]
                          + reinterpret_cast<const float*>(&b)[j]
                          + reinterpret_cast<const float*>(&c)[j]
                          + reinterpret_cast<const float*>(&e)[j];
            const float norm = sqrtf(s);
            const float v = 1.f / fmaxf(norm, EPSV);
            reinterpret_cast<float*>(&iv)[j] = v * 0.0625f;   // fold 1/16
            const float r = norm * v;
            reinterpret_cast<float*>(&rr)[j] = r * r;
        }
        *reinterpret_cast<float4*>(&inv1[(size_t)nk * PS_ + p0]) = iv;
        *reinterpret_cast<float4*>(&rloc[(size_t)nk * PS_ + p0]) = rr;
    }
}

// K6: inv2[n,p] = 1/max(sqrt(sum_k rloc),EPS) — float4 quads. (unchanged)
__global__ __launch_bounds__(256) void k6_inv2(
    const float* __restrict__ rloc, float* __restrict__ inv2)
{
    const int n = blockIdx.x;
    const int t = threadIdx.x;
    if (t < 250) {
        const int p0 = 4 * t;
        float4 s = make_float4(0, 0, 0, 0);
        for (int k = 0; k < K_; ++k) {
            const float4 r = ld4(&rloc[(size_t)(n * K_ + k) * PS_ + p0]);
            s = f4add(s, r);
        }
        float4 o;
        o.x = 1.f / fmaxf(sqrtf(s.x), EPSV);
        o.y = 1.f / fmaxf(sqrtf(s.y), EPSV);
        o.z = 1.f / fmaxf(sqrtf(s.z), EPSV);
        o.w = 1.f / fmaxf(sqrtf(s.w), EPSV);
        *reinterpret_cast<float4*>(&inv2[n * PS_ + p0]) = o;
    }
}

// ---------------------------------------------------------------------------
// K7w: WRITE pass — scl/t2 now in REGISTERS (thread t's stores only touch
//      p ∈ [4t, 4t+6]: 7 inv1·inv2 products + 7 sa-box windows computed once
//      in the prologue). Removes the 8 KB scl/t2 LDS stage → 39.7 KB LDS
//      → 4 blocks/CU (if VGPR permits). Stragglers compute theirs directly.
// ---------------------------------------------------------------------------
__global__ __launch_bounds__(256) void k7_write(
    const float* __restrict__ sa, const float* __restrict__ xnT,
    const float* __restrict__ cent, const float* __restrict__ inv1,
    const float* __restrict__ inv2, float* __restrict__ outl)
{
    __shared__ float  sa_s[1248];
    __shared__ float4 cs_q[2][4][SL_ + 1];

    const int b  = blockIdx.x;            // ((n*K + k)*4 + cq)
    const int cq = b & 3;
    const int nk = b >> 2;
    const int n  = nk >> 6, k = nk & 63;
    const int t  = threadIdx.x;

    for (int i = t; i < HW_; i += 256) sa_s[i] = sa[(size_t)nk * HW_ + i];
    __syncthreads();

    // Register prologue for t<249: prodv[u] = inv1·inv2 at p=4t+u,
    // ttv[u] = B(p)·prodv[u], u=0..6. B via 13 sa-colsums + window tree,
    // row-crossing select at dB (verified window algebra from K4).
    float prodv[7], ttv[7];
    if (t < 249) {
        const int p0 = 4 * t;
        const int hp0 = p0 / WP_;
        const int wp0 = p0 - hp0 * WP_;
        const int bB  = p0 + 3 * hp0;     // linear colsum index of p0
        const int dB  = WP_ - wp0;        // crossing position within u=0..6
        const float* r0 = &sa_s[bB];
        float c[13];
#pragma unroll
        for (int u = 0; u < 13; ++u)
            c[u] = r0[u] + r0[u + W_] + r0[u + 2 * W_] + r0[u + 3 * W_];
        float cc[12];
#pragma unroll
        for (int u = 0; u < 12; ++u) cc[u] = c[u] + c[u + 1];
        float wv[10];
#pragma unroll
        for (int u = 0; u < 10; ++u) wv[u] = cc[u] + cc[u + 2];
        const float* i1 = inv1 + (size_t)nk * PS_ + p0;
        const float* i2 = inv2 + (size_t)n * PS_ + p0;
#pragma unroll
        for (int u = 0; u < 7; ++u) {
            const float pr = i1[u] * i2[u];
            const float Bv = (u < dB) ? wv[u] : wv[u + 3];
            prodv[u] = pr;
            ttv[u]   = Bv * pr;
        }
    }

    const float* xb = xnT + (size_t)n * C_ * HW_;
    float* ob = outl + (size_t)nk * CP_;

#pragma unroll
    for (int iter = 0; iter < 4; ++iter) {
        const int m = iter;
        const int c0 = cq * 32 + m;       // 8 channels: c0 + 4j, all ≡ m mod 4
        __syncthreads();                  // prior iteration's cs_q readers done
        COLSUM_STRIP(cs_q, sa_s, xb, c0)
        __syncthreads();
        const float* ck = &cent[k * C_ + c0];
        const float ce0 = ck[0],  ce1 = ck[4],  ce2 = ck[8],  ce3 = ck[12];
        const float ce4 = ck[16], ce5 = ck[20], ce6 = ck[24], ce7 = ck[28];
        float* ob0 = ob + (size_t)(c0 + 0)  * P_;
        float* ob1 = ob + (size_t)(c0 + 4)  * P_;
        float* ob2 = ob + (size_t)(c0 + 8)  * P_;
        float* ob3 = ob + (size_t)(c0 + 12) * P_;
        float* ob4 = ob + (size_t)(c0 + 16) * P_;
        float* ob5 = ob + (size_t)(c0 + 20) * P_;
        float* ob6 = ob + (size_t)(c0 + 24) * P_;
        float* ob7 = ob + (size_t)(c0 + 28) * P_;

        if (t < 249) {                                 // vector: p ∈ [m, m+996)
            const int p0 = m + 4 * t;
            const int hp0 = p0 / WP_;
            const int wp0 = p0 - hp0 * WP_;
            const int b0 = p0 + 3 * hp0;
            const int d  = WP_ - wp0;
            const float sc0 = prodv[m + 0], sc1 = prodv[m + 1];
            const float sc2 = prodv[m + 2], sc3 = prodv[m + 3];
            const float tt0 = ttv[m + 0], tt1 = ttv[m + 1];
            const float tt2 = ttv[m + 2], tt3 = ttv[m + 3];
            float4 A0, A1, A2, A3, Q0, Q1, Q2, Q3;
            WINDOW10(cs_q[0], b0, d, A0, A1, A2, A3)
            WINDOW10(cs_q[1], b0, d, Q0, Q1, Q2, Q3)
            *reinterpret_cast<float4*>(ob0 + p0) =
                make_float4(A0.x * sc0 - ce0 * tt0, A1.x * sc1 - ce0 * tt1,
                            A2.x * sc2 - ce0 * tt2, A3.x * sc3 - ce0 * tt3);
            *reinterpret_cast<float4*>(ob1 + p0) =
                make_float4(A0.y * sc0 - ce1 * tt0, A1.y * sc1 - ce1 * tt1,
                            A2.y * sc2 - ce1 * tt2, A3.y * sc3 - ce1 * tt3);
            *reinterpret_cast<float4*>(ob2 + p0) =
                make_float4(A0.z * sc0 - ce2 * tt0, A1.z * sc1 - ce2 * tt1,
                            A2.z * sc2 - ce2 * tt2, A3.z * sc3 - ce2 * tt3);
            *reinterpret_cast<float4*>(ob3 + p0) =
                make_float4(A0.w * sc0 - ce3 * tt0, A1.w * sc1 - ce3 * tt1,
                            A2.w * sc2 - ce3 * tt2, A3.w * sc3 - ce3 * tt3);
            *reinterpret_cast<float4*>(ob4 + p0) =
                make_float4(Q0.x * sc0 - ce4 * tt0, Q1.x * sc1 - ce4 * tt1,
                            Q2.x * sc2 - ce4 * tt2, Q3.x * sc3 - ce4 * tt3);
            *reinterpret_cast<float4*>(ob5 + p0) =
                make_float4(Q0.y * sc0 - ce5 * tt0, Q1.y * sc1 - ce5 * tt1,
                            Q2.y * sc2 - ce5 * tt2, Q3.y * sc3 - ce5 * tt3);
            *reinterpret_cast<float4*>(ob6 + p0) =
                make_float4(Q0.z * sc0 - ce6 * tt0, Q1.z * sc1 - ce6 * tt1,
                            Q2.z * sc2 - ce6 * tt2, Q3.z * sc3 - ce6 * tt3);
            *reinterpret_cast<float4*>(ob7 + p0) =
                make_float4(Q0.w * sc0 - ce7 * tt0, Q1.w * sc1 - ce7 * tt1,
                            Q2.w * sc2 - ce7 * tt2, Q3.w * sc3 - ce7 * tt3);
        } else if (t < 252) {                          // 3 scalar stragglers
            const int u = t - 249;
            const int p = (u < m) ? u : 996 + u;       // {0..m-1} ∪ {m+996..998}
            const int hp = p / WP_, wp = p - hp * WP_;
            float bs = 0.f;
#pragma unroll
            for (int dh = 0; dh < 4; ++dh) {
                const float* r = &sa_s[(hp + dh) * W_ + wp];
                bs += r[0] + r[1] + r[2] + r[3];
            }
            const float sc = inv1[(size_t)nk * PS_ + p] * inv2[n * PS_ + p];
            const float tt = bs * sc;
            const int base = hp * W_ + wp;
            const float4 a0 = cs_q[0][(base + 0) & 3][(base + 0) >> 2];
            const float4 a1 = cs_q[0][(base + 1) & 3][(base + 1) >> 2];
            const float4 a2 = cs_q[0][(base + 2) & 3][(base + 2) >> 2];
            const float4 a3 = cs_q[0][(base + 3) & 3][(base + 3) >> 2];
            const float4 q0 = cs_q[1][(base + 0) & 3][(base + 0) >> 2];
            const float4 q1 = cs_q[1][(base + 1) & 3][(base + 1) >> 2];
            const float4 q2 = cs_q[1][(base + 2) & 3][(base + 2) >> 2];
            const float4 q3 = cs_q[1][(base + 3) & 3][(base + 3) >> 2];
            ob0[p] = (a0.x + a1.x + a2.x + a3.x) * sc - ce0 * tt;
            ob1[p] = (a0.y + a1.y + a2.y + a3.y) * sc - ce1 * tt;
            ob2[p] = (a0.z + a1.z + a2.z + a3.z) * sc - ce2 * tt;
            ob3[p] = (a0.w + a1.w + a2.w + a3.w) * sc - ce3 * tt;
            ob4[p] = (q0.x + q1.x + q2.x + q3.x) * sc - ce4 * tt;
            ob5[p] = (q0.y + q1.y + q2.y + q3.y) * sc - ce5 * tt;
            ob6[p] = (q0.z + q1.z + q2.z + q3.z) * sc - ce6 * tt;
            ob7[p] = (q0.w + q1.w + q2.w + q3.w) * sc - ce7 * tt;
        }
    }
}

// ---------------------------------------------------------------------------
extern "C" void kernel_launch(void* const* d_in, const int* in_sizes, int n_in,
                              void* d_out, int out_size, void* d_ws, size_t ws_size,
                              hipStream_t stream)
{
    const float* x      = (const float*)d_in[0];
    const float* conv_w = (const float*)d_in[1];
    const float* cent   = (const float*)d_in[2];
    float* out = (float*)d_out;
    float* ws  = (float*)d_ws;

    // workspace layout (floats); p-indexed buffers use padded stride 1000
    float* xnT  = ws;                       // 614400
    float* xnP  = ws + 614400;              // 614400
    float* sa   = ws + 1228800;             // 307200
    float* vg_u = ws + 1536000;             // 32768
    float* vg_r = ws + 1568768;             // 256
    float* nsqp = ws + 1569024;             // 1024*1000 = 1024000
    float* inv1 = ws + 2593024;             // 256*1000  = 256000
    float* rloc = ws + 2849024;             // 256*1000  = 256000
    float* inv2 = ws + 3105024;             // 4*1000    = 4000

    float* outl = out + (size_t)N_ * KC_;   // output 1 region

    k1_norm_softmax<<<N_ * H_ * 2, 256, 0, stream>>>(x, conv_w, xnT, xnP, sa);
    k4_merged<<<256 + N_ * K_ * 4, 256, 0, stream>>>(sa, xnT, xnP, cent,
                                                     nsqp, vg_u, vg_r);
    k5_merged<<<256 + N_, 256, 0, stream>>>(nsqp, inv1, rloc, vg_u, vg_r, out);
    k6_inv2<<<N_, 256, 0, stream>>>(rloc, inv2);
    k7_write<<<N_ * K_ * 4, 256, 0, stream>>>(sa, xnT, cent, inv1, inv2, outl);
}

// Round 14
// 110.649 us; speedup vs baseline: 1.0177x; 1.0177x over previous
//
#include <hip/hip_runtime.h>
#include <math.h>

#define EPSV 1e-12f

namespace {
constexpr int N_  = 4;
constexpr int C_  = 128;
constexpr int H_  = 30;
constexpr int W_  = 40;
constexpr int K_  = 64;
constexpr int HW_ = H_ * W_;        // 1200
constexpr int HP_ = 27;             // H+1-4
constexpr int WP_ = 37;             // W+1-4
constexpr int P_  = HP_ * WP_;      // 999
constexpr int PS_ = 1000;           // padded stride for p-indexed buffers
constexpr int KC_ = K_ * C_;        // 8192
constexpr int CP_ = C_ * P_;        // 127872 floats per (n,k) slab
constexpr int CS_ = HP_ * W_;       // 1080 colsum rows
constexpr int SL_ = CS_ / 4;        // 270 vector slots
constexpr int CVP_ = 132;           // padded row stride for conv_s / xrowT
constexpr int WH_ = 20;             // w-half width for K1
}

static __device__ __forceinline__ float4 ld4(const float* p) {
    return *reinterpret_cast<const float4*>(p);
}
static __device__ __forceinline__ float dot4(float4 a, float4 b) {
    return a.x * b.x + a.y * b.y + a.z * b.z + a.w * b.w;
}
static __device__ __forceinline__ float4 f4add(float4 a, float4 b) {
    return make_float4(a.x + b.x, a.y + b.y, a.z + b.z, a.w + b.w);
}
static __device__ __forceinline__ float4 f4mul(float4 a, float4 b) {
    return make_float4(a.x * b.x, a.y * b.y, a.z * b.z, a.w * b.w);
}

// ---------------------------------------------------------------------------
// K1: per (n,h,w-half) — 240 blocks. L2-normalize x over channels, write xn
//     in two layouts, conv scores + softmax. Norm and softmax are 8-way
//     lane-parallel per w (shfl_xor trees); exp values kept in regs.
// ---------------------------------------------------------------------------
__global__ __launch_bounds__(256) void k1_norm_softmax(
    const float* __restrict__ x, const float* __restrict__ conv_w,
    float* __restrict__ xnT, float* __restrict__ xnP, float* __restrict__ sa)
{
    __shared__ float xrow[C_ * WH_];      // [c][20]
    __shared__ float conv_s[K_ * CVP_];   // [k][132]
    __shared__ float xrowT[WH_ * CVP_];   // [w][132]
    __shared__ float invn[WH_];
    __shared__ float s_s[K_ * WH_];       // [k][20]

    const int b  = blockIdx.x;            // (n*H + h)*2 + wh
    const int wh = b & 1;
    const int nh = b >> 1;
    const int n = nh / H_, h = nh - n * H_;
    const int wbase = wh * WH_;
    const int t = threadIdx.x;

    for (int i = t; i < C_ * WH_; i += 256) {
        const int c = i / WH_, w = i - c * WH_;
        xrow[i] = x[(size_t)(n * C_ + c) * HW_ + h * W_ + wbase + w];
    }
    for (int i = t; i < K_ * C_; i += 256) {
        const int k = i >> 7, c = i & 127;
        conv_s[k * CVP_ + c] = conv_w[i];
    }
    __syncthreads();

    // norm: 8 lanes per w; c = g + 8i (banks (20g+w)%32 — conflict-free)
    if (t < 8 * WH_) {
        const int w = t >> 3, g = t & 7;
        float s = 0.f;
#pragma unroll
        for (int i = 0; i < 16; ++i) {
            const float v = xrow[(g + 8 * i) * WH_ + w];
            s += v * v;
        }
        s += __shfl_xor(s, 1);
        s += __shfl_xor(s, 2);
        s += __shfl_xor(s, 4);
        if (g == 0) invn[w] = 1.f / fmaxf(sqrtf(s), EPSV);
    }
    __syncthreads();

    for (int i = t; i < C_ * WH_; i += 256) {
        const int c = i / WH_, w = i - c * WH_;
        const float v = xrow[i] * invn[w];
        xrow[i] = v;
        xnT[(size_t)(n * C_ + c) * HW_ + h * W_ + wbase + w] = v;
    }
    __syncthreads();

    for (int i = t; i < WH_ * C_; i += 256) {
        const int w = i >> 7, c = i & 127;
        const float v = xrow[c * WH_ + w];
        xnP[((size_t)n * HW_ + h * W_ + wbase + w) * C_ + c] = v;
        xrowT[w * CVP_ + c] = v;
    }
    __syncthreads();

    // scores: t = (k, wq); each handles 5 w's; conv chunk (8 float4) in regs
    {
        const int k = t >> 2, wq = t & 3;
        float acc[5] = {};
        const float* convk = &conv_s[k * CVP_];
        for (int ch = 0; ch < 4; ++ch) {
            float4 cv0 = ld4(convk + ch * 32 + 0),  cv1 = ld4(convk + ch * 32 + 4);
            float4 cv2 = ld4(convk + ch * 32 + 8),  cv3 = ld4(convk + ch * 32 + 12);
            float4 cv4 = ld4(convk + ch * 32 + 16), cv5 = ld4(convk + ch * 32 + 20);
            float4 cv6 = ld4(convk + ch * 32 + 24), cv7 = ld4(convk + ch * 32 + 28);
#pragma unroll
            for (int j = 0; j < 5; ++j) {
                const float* xw = &xrowT[(wq * 5 + j) * CVP_ + ch * 32];
                acc[j] += dot4(cv0, ld4(xw)) + dot4(cv1, ld4(xw + 4))
                        + dot4(cv2, ld4(xw + 8)) + dot4(cv3, ld4(xw + 12))
                        + dot4(cv4, ld4(xw + 16)) + dot4(cv5, ld4(xw + 20))
                        + dot4(cv6, ld4(xw + 24)) + dot4(cv7, ld4(xw + 28));
            }
        }
        float* sd = &s_s[k * WH_ + wq * 5];
#pragma unroll
        for (int j = 0; j < 5; ++j) sd[j] = acc[j];
    }
    __syncthreads();

    // softmax: 8 lanes per w; k = g + 8kk (conflict-free banks); exp in regs
    if (t < 8 * WH_) {
        const int w = t >> 3, g = t & 7;
        float sv[8];
#pragma unroll
        for (int kk = 0; kk < 8; ++kk) sv[kk] = s_s[(g + 8 * kk) * WH_ + w];
        float m = fmaxf(fmaxf(fmaxf(sv[0], sv[1]), fmaxf(sv[2], sv[3])),
                        fmaxf(fmaxf(sv[4], sv[5]), fmaxf(sv[6], sv[7])));
        m = fmaxf(m, __shfl_xor(m, 1));
        m = fmaxf(m, __shfl_xor(m, 2));
        m = fmaxf(m, __shfl_xor(m, 4));
        float ex[8];
        float sum = 0.f;
#pragma unroll
        for (int kk = 0; kk < 8; ++kk) { ex[kk] = expf(sv[kk] - m); sum += ex[kk]; }
        sum += __shfl_xor(sum, 1);
        sum += __shfl_xor(sum, 2);
        sum += __shfl_xor(sum, 4);
        const float inv = 1.f / sum;
#pragma unroll
        for (int kk = 0; kk < 8; ++kk)
            sa[(size_t)(n * K_ + g + 8 * kk) * HW_ + h * W_ + wbase + w] = ex[kk] * inv;
    }
}

// ---------------------------------------------------------------------------
// Strip colsum: thread t<140 owns (channel-quad q2 = t/70, strip = t%70).
// A strip = 4 output rows × one w-float4 for 4 channels {cA,cA+4,cA+8,cA+12}.
// Loads 7 rows once (28 dwordx4) → 16 pixel-outputs.
// ---------------------------------------------------------------------------
#define COLSUM_STRIP(cs_q, sa_s, xb, cA_base)                                   \
    if (t < 140) {                                                              \
        const int q2 = t / 70, item = t - q2 * 70;                              \
        const int hq = item / 10, wq = item - hq * 10;                          \
        const int h0 = 4 * hq;                                                  \
        const int nh = (hq < 6) ? 4 : 3;                                        \
        const int cA = (cA_base) + q2 * 16;                                     \
        const float* xp0 = xb + (size_t)(cA + 0)  * HW_ + h0 * W_ + 4 * wq;     \
        const float* xp1 = xb + (size_t)(cA + 4)  * HW_ + h0 * W_ + 4 * wq;     \
        const float* xp2 = xb + (size_t)(cA + 8)  * HW_ + h0 * W_ + 4 * wq;     \
        const float* xp3 = xb + (size_t)(cA + 12) * HW_ + h0 * W_ + 4 * wq;     \
        const float* sap = &sa_s[h0 * W_ + 4 * wq];                             \
        float4 p0[7], p1[7], p2[7], p3[7];                                      \
        _Pragma("unroll")                                                       \
        for (int r = 0; r < 7; ++r) {                                           \
            const float4 sv = ld4(sap + r * W_);                                \
            p0[r] = f4mul(sv, ld4(xp0 + r * W_));                               \
            p1[r] = f4mul(sv, ld4(xp1 + r * W_));                               \
            p2[r] = f4mul(sv, ld4(xp2 + r * W_));                               \
            p3[r] = f4mul(sv, ld4(xp3 + r * W_));                               \
        }                                                                       \
        _Pragma("unroll")                                                       \
        for (int hh = 0; hh < 4; ++hh) {                                        \
            if (hh < nh) {                                                      \
                const float4 c0v = f4add(f4add(p0[hh], p0[hh+1]), f4add(p0[hh+2], p0[hh+3])); \
                const float4 c1v = f4add(f4add(p1[hh], p1[hh+1]), f4add(p1[hh+2], p1[hh+3])); \
                const float4 c2v = f4add(f4add(p2[hh], p2[hh+1]), f4add(p2[hh+2], p2[hh+3])); \
                const float4 c3v = f4add(f4add(p3[hh], p3[hh+1]), f4add(p3[hh+2], p3[hh+3])); \
                const int s = 10 * (h0 + hh) + wq;                              \
                cs_q[q2][0][s] = make_float4(c0v.x, c1v.x, c2v.x, c3v.x);       \
                cs_q[q2][1][s] = make_float4(c0v.y, c1v.y, c2v.y, c3v.y);       \
                cs_q[q2][2][s] = make_float4(c0v.z, c1v.z, c2v.z, c3v.z);       \
                cs_q[q2][3][s] = make_float4(c0v.w, c1v.w, c2v.w, c3v.w);       \
            }                                                                   \
        }                                                                       \
    }

// 10-value window read over one quad array csq[4][SL_+1].
#define WINDOW10(csq, b0, d, A0, A1, A2, A3)                                    \
    {                                                                           \
        float4 v0 = csq[(b0 + 0) & 3][(b0 + 0) >> 2];                           \
        float4 v1 = csq[(b0 + 1) & 3][(b0 + 1) >> 2];                           \
        float4 v2 = csq[(b0 + 2) & 3][(b0 + 2) >> 2];                           \
        float4 v3 = csq[(b0 + 3) & 3][(b0 + 3) >> 2];                           \
        float4 v4 = csq[(b0 + 4) & 3][(b0 + 4) >> 2];                           \
        float4 v5 = csq[(b0 + 5) & 3][(b0 + 5) >> 2];                           \
        float4 v6 = csq[(b0 + 6) & 3][(b0 + 6) >> 2];                           \
        float4 v7 = csq[(b0 + 7) & 3][(b0 + 7) >> 2];                           \
        float4 v8 = csq[(b0 + 8) & 3][(b0 + 8) >> 2];                           \
        float4 v9 = csq[(b0 + 9) & 3][(b0 + 9) >> 2];                           \
        const float4 t0 = f4add(v0, v1), t1 = f4add(v1, v2), t2 = f4add(v2, v3);\
        const float4 t3 = f4add(v3, v4), t4 = f4add(v4, v5), t5 = f4add(v5, v6);\
        const float4 t6 = f4add(v6, v7), t7 = f4add(v7, v8), t8 = f4add(v8, v9);\
        const float4 w0 = f4add(t0, t2), w1 = f4add(t1, t3), w2 = f4add(t2, t4);\
        const float4 w3 = f4add(t3, t5), w4 = f4add(t4, t6), w5 = f4add(t5, t7);\
        const float4 w6 = f4add(t6, t8);                                        \
        A0 = (0 < d) ? w0 : w3;                                                 \
        A1 = (1 < d) ? w1 : w4;                                                 \
        A2 = (2 < d) ? w2 : w5;                                                 \
        A3 = (3 < d) ? w3 : w6;                                                 \
    }

// ---------------------------------------------------------------------------
// K4m: merged launch. blocks[0,256): vlad_global; blocks[256,1280): norm pass
//      (strip colsum, 8 channels/iteration, 4 iterations).
// ---------------------------------------------------------------------------
__global__ __launch_bounds__(256) void k4_merged(
    const float* __restrict__ sa, const float* __restrict__ xnT,
    const float* __restrict__ xnP, const float* __restrict__ cent,
    float* __restrict__ nsqp, float* __restrict__ vg_u,
    float* __restrict__ vg_r)
{
    __shared__ float  sa_s[1248];         // 31 rows + pad (strip/window overreads)
    __shared__ float4 cs_q[2][4][SL_ + 1];
    __shared__ float  gs[256], bss[256];
    __shared__ float  red[2];

    const int t = threadIdx.x;

    if (blockIdx.x < 256) {
        const int b = blockIdx.x;         // n*K + k
        const int n = b >> 6, k = b & 63;
        const int c = t & 127, half = t >> 7;
        constexpr int HHW = HW_ / 2;      // 600

        const float* sarow = &sa[(size_t)b * HW_ + half * HHW];
        const float* xp = &xnP[((size_t)n * HW_ + half * HHW) * C_ + c];
        float g0 = 0.f, g1 = 0.f, g2 = 0.f, g3 = 0.f;
        float b0 = 0.f, b1 = 0.f, b2 = 0.f, b3 = 0.f;
        for (int pix = 0; pix < HHW; pix += 4) {
            const float s0 = sarow[pix + 0], s1 = sarow[pix + 1];
            const float s2 = sarow[pix + 2], s3 = sarow[pix + 3];
            g0 += s0 * xp[(size_t)(pix + 0) * C_];
            g1 += s1 * xp[(size_t)(pix + 1) * C_];
            g2 += s2 * xp[(size_t)(pix + 2) * C_];
            g3 += s3 * xp[(size_t)(pix + 3) * C_];
            b0 += s0; b1 += s1; b2 += s2; b3 += s3;
        }
        gs[t]  = (g0 + g1) + (g2 + g3);
        bss[t] = (b0 + b1) + (b2 + b3);
        __syncthreads();

        float vg = 0.f;
        if (t < 128) {
            vg = (gs[t] + gs[t + 128]) - cent[k * C_ + c] * (bss[t] + bss[t + 128]);
            float nsq = vg * vg;
            for (int off = 32; off >= 1; off >>= 1) nsq += __shfl_down(nsq, off);
            if ((t & 63) == 0) red[t >> 6] = nsq;
        }
        __syncthreads();
        const float tot  = red[0] + red[1];
        const float norm = sqrtf(tot);
        const float iv   = 1.f / fmaxf(norm, EPSV);
        if (t < 128) vg_u[(size_t)b * C_ + t] = vg * iv;
        if (t == 0) { const float rr = norm * iv; vg_r[b] = rr * rr; }
        return;
    }

    const int b  = blockIdx.x - 256;      // ((n*K + k)*4 + cq)
    const int cq = b & 3;
    const int nk = b >> 2;
    const int n  = nk >> 6, k = nk & 63;

    for (int i = t; i < HW_; i += 256) sa_s[i] = sa[(size_t)nk * HW_ + i];
    __syncthreads();

    // sa box-sum windows (B) in registers (thread t<250 owns p0 = 4t..4t+3)
    int b0 = 0, d = 4;
    float Bw0 = 0.f, Bw1 = 0.f, Bw2 = 0.f, Bw3 = 0.f;
    if (t < 250) {
        const int p0 = 4 * t;
        const int hp0 = p0 / WP_;
        const int wp0 = p0 - hp0 * WP_;
        b0 = p0 + 3 * hp0;
        d  = WP_ - wp0;
        const float* r0 = &sa_s[hp0 * W_ + wp0];
        float sc[10];
#pragma unroll
        for (int j = 0; j < 10; ++j)
            sc[j] = r0[j] + r0[j + W_] + r0[j + 2 * W_] + r0[j + 3 * W_];
        const float u0 = sc[0] + sc[1], u1 = sc[1] + sc[2], u2 = sc[2] + sc[3];
        const float u3 = sc[3] + sc[4], u4 = sc[4] + sc[5], u5 = sc[5] + sc[6];
        const float u6 = sc[6] + sc[7], u7 = sc[7] + sc[8], u8 = sc[8] + sc[9];
        const float wB0 = u0 + u2, wB1 = u1 + u3, wB2 = u2 + u4;
        const float wB3 = u3 + u5, wB4 = u4 + u6, wB5 = u5 + u7, wB6 = u6 + u8;
        Bw0 = (0 < d) ? wB0 : wB3;
        Bw1 = (1 < d) ? wB1 : wB4;
        Bw2 = (2 < d) ? wB2 : wB5;
        Bw3 = (3 < d) ? wB3 : wB6;
    }

    float nsq0 = 0.f, nsq1 = 0.f, nsq2 = 0.f, nsq3 = 0.f;
    const float* xb = xnT + (size_t)n * C_ * HW_;

    for (int iter = 0; iter < 4; ++iter) {
        const int c0 = cq * 32 + iter;    // 8 channels: c0 + 4j, j=0..7
        __syncthreads();                  // prior iteration's cs_q readers done
        COLSUM_STRIP(cs_q, sa_s, xb, c0)
        __syncthreads();
        if (t < 250) {
            const float* ck = &cent[k * C_ + c0];
            const float4 ceA = make_float4(ck[0], ck[4], ck[8], ck[12]);
            const float4 ceB = make_float4(ck[16], ck[20], ck[24], ck[28]);
            float4 A0, A1, A2, A3, Q0, Q1, Q2, Q3;
            WINDOW10(cs_q[0], b0, d, A0, A1, A2, A3)
            WINDOW10(cs_q[1], b0, d, Q0, Q1, Q2, Q3)
            {
                const float4 e = make_float4(A0.x - ceA.x * Bw0, A0.y - ceA.y * Bw0,
                                             A0.z - ceA.z * Bw0, A0.w - ceA.w * Bw0);
                const float4 f = make_float4(Q0.x - ceB.x * Bw0, Q0.y - ceB.y * Bw0,
                                             Q0.z - ceB.z * Bw0, Q0.w - ceB.w * Bw0);
                nsq0 += dot4(e, e) + dot4(f, f);
            }
            {
                const float4 e = make_float4(A1.x - ceA.x * Bw1, A1.y - ceA.y * Bw1,
                                             A1.z - ceA.z * Bw1, A1.w - ceA.w * Bw1);
                const float4 f = make_float4(Q1.x - ceB.x * Bw1, Q1.y - ceB.y * Bw1,
                                             Q1.z - ceB.z * Bw1, Q1.w - ceB.w * Bw1);
                nsq1 += dot4(e, e) + dot4(f, f);
            }
            {
                const float4 e = make_float4(A2.x - ceA.x * Bw2, A2.y - ceA.y * Bw2,
                                             A2.z - ceA.z * Bw2, A2.w - ceA.w * Bw2);
                const float4 f = make_float4(Q2.x - ceB.x * Bw2, Q2.y - ceB.y * Bw2,
                                             Q2.z - ceB.z * Bw2, Q2.w - ceB.w * Bw2);
                nsq2 += dot4(e, e) + dot4(f, f);
            }
            {
                const float4 e = make_float4(A3.x - ceA.x * Bw3, A3.y - ceA.y * Bw3,
                                             A3.z - ceA.z * Bw3, A3.w - ceA.w * Bw3);
                const float4 f = make_float4(Q3.x - ceB.x * Bw3, Q3.y - ceB.y * Bw3,
                                             Q3.z - ceB.z * Bw3, Q3.w - ceB.w * Bw3);
                nsq3 += dot4(e, e) + dot4(f, f);
            }
        }
    }
    if (t < 250) {
        *reinterpret_cast<float4*>(&nsqp[(size_t)b * PS_ + 4 * t]) =
            make_float4(nsq0 * 0.00390625f, nsq1 * 0.00390625f,
                        nsq2 * 0.00390625f, nsq3 * 0.00390625f);
    }
}

// ---------------------------------------------------------------------------
// K5m: blocks[0,256): combine cq partials (float4 quads); [256,260): vg fin.
// ---------------------------------------------------------------------------
__global__ __launch_bounds__(256) void k5_merged(
    const float* __restrict__ nsqp, float* __restrict__ inv1,
    float* __restrict__ rloc, const float* __restrict__ vg_u,
    const float* __restrict__ vg_r, float* __restrict__ out)
{
    const int t = threadIdx.x;
    if (blockIdx.x >= 256) {
        const int n = blockIdx.x - 256;
        __shared__ float inv2s;
        if (t == 0) {
            float s = 0.f;
            for (int k = 0; k < K_; ++k) s += vg_r[n * K_ + k];
            inv2s = 1.f / fmaxf(sqrtf(s), EPSV);
        }
        __syncthreads();
        const float inv2 = inv2s;
        for (int i = t; i < KC_; i += 256)
            out[(size_t)n * KC_ + i] = vg_u[(size_t)n * KC_ + i] * inv2;
        return;
    }
    const int nk = blockIdx.x;
    if (t < 250) {
        const int p0 = 4 * t;
        const float4 a = ld4(&nsqp[(size_t)(nk * 4 + 0) * PS_ + p0]);
        const float4 b = ld4(&nsqp[(size_t)(nk * 4 + 1) * PS_ + p0]);
        const float4 c = ld4(&nsqp[(size_t)(nk * 4 + 2) * PS_ + p0]);
        const float4 e = ld4(&nsqp[(size_t)(nk * 4 + 3) * PS_ + p0]);
        float4 iv, rr;
#pragma unroll
        for (int j = 0; j < 4; ++j) {
            const float s = reinterpret_cast<const float*>(&a)[j]
                          + reinterpret_cast<const float*>(&b)[j]
                          + reinterpret_cast<const float*>(&c)[j]
                          + reinterpret_cast<const float*>(&e)[j];
            const float norm = sqrtf(s);
            const float v = 1.f / fmaxf(norm, EPSV);
            reinterpret_cast<float*>(&iv)[j] = v * 0.0625f;   // fold 1/16
            const float r = norm * v;
            reinterpret_cast<float*>(&rr)[j] = r * r;
        }
        *reinterpret_cast<float4*>(&inv1[(size_t)nk * PS_ + p0]) = iv;
        *reinterpret_cast<float4*>(&rloc[(size_t)nk * PS_ + p0]) = rr;
    }
}

// K6: inv2[n,p] = 1/max(sqrt(sum_k rloc),EPS) — float4 quads.
__global__ __launch_bounds__(256) void k6_inv2(
    const float* __restrict__ rloc, float* __restrict__ inv2)
{
    const int n = blockIdx.x;
    const int t = threadIdx.x;
    if (t < 250) {
        const int p0 = 4 * t;
        float4 s = make_float4(0, 0, 0, 0);
        for (int k = 0; k < K_; ++k) {
            const float4 r = ld4(&rloc[(size_t)(n * K_ + k) * PS_ + p0]);
            s = f4add(s, r);
        }
        float4 o;
        o.x = 1.f / fmaxf(sqrtf(s.x), EPSV);
        o.y = 1.f / fmaxf(sqrtf(s.y), EPSV);
        o.z = 1.f / fmaxf(sqrtf(s.z), EPSV);
        o.w = 1.f / fmaxf(sqrtf(s.w), EPSV);
        *reinterpret_cast<float4*>(&inv2[n * PS_ + p0]) = o;
    }
}

// ---------------------------------------------------------------------------
// K7w: WRITE pass — strip colsum (8 ch/iter), 10-read windows, aligned
//      float4 stores (m = iter, channels all ≡ m mod 4).
// ---------------------------------------------------------------------------
__global__ __launch_bounds__(256) void k7_write(
    const float* __restrict__ sa, const float* __restrict__ xnT,
    const float* __restrict__ cent, const float* __restrict__ inv1,
    const float* __restrict__ inv2, float* __restrict__ outl)
{
    __shared__ float  sa_s[1248];
    __shared__ float  scl_s[P_];
    __shared__ float  t2_s[P_];
    __shared__ float4 cs_q[2][4][SL_ + 1];

    const int b  = blockIdx.x;            // ((n*K + k)*4 + cq)
    const int cq = b & 3;
    const int nk = b >> 2;
    const int n  = nk >> 6, k = nk & 63;
    const int t  = threadIdx.x;

    for (int i = t; i < HW_; i += 256) sa_s[i] = sa[(size_t)nk * HW_ + i];
    __syncthreads();
    for (int p = t; p < P_; p += 256) {
        const int hp = p / WP_, wp = p - hp * WP_;
        float bs = 0.f;
#pragma unroll
        for (int dh = 0; dh < 4; ++dh) {
            const float* r = &sa_s[(hp + dh) * W_ + wp];
            bs += r[0] + r[1] + r[2] + r[3];
        }
        const float sc = inv1[(size_t)nk * PS_ + p] * inv2[n * PS_ + p];
        scl_s[p] = sc;
        t2_s[p]  = bs * sc;
    }

    const float* xb = xnT + (size_t)n * C_ * HW_;
    float* ob = outl + (size_t)nk * CP_;

    for (int iter = 0; iter < 4; ++iter) {
        const int m = iter;
        const int c0 = cq * 32 + m;       // 8 channels: c0 + 4j, all ≡ m mod 4
        __syncthreads();                  // prior iteration's cs_q readers done
        COLSUM_STRIP(cs_q, sa_s, xb, c0)
        __syncthreads();
        const float* ck = &cent[k * C_ + c0];
        const float ce0 = ck[0],  ce1 = ck[4],  ce2 = ck[8],  ce3 = ck[12];
        const float ce4 = ck[16], ce5 = ck[20], ce6 = ck[24], ce7 = ck[28];
        float* ob0 = ob + (size_t)(c0 + 0)  * P_;
        float* ob1 = ob + (size_t)(c0 + 4)  * P_;
        float* ob2 = ob + (size_t)(c0 + 8)  * P_;
        float* ob3 = ob + (size_t)(c0 + 12) * P_;
        float* ob4 = ob + (size_t)(c0 + 16) * P_;
        float* ob5 = ob + (size_t)(c0 + 20) * P_;
        float* ob6 = ob + (size_t)(c0 + 24) * P_;
        float* ob7 = ob + (size_t)(c0 + 28) * P_;

        if (t < 249) {                                 // vector: p ∈ [m, m+996)
            const int p0 = m + 4 * t;
            const int hp0 = p0 / WP_;
            const int wp0 = p0 - hp0 * WP_;
            const int b0 = p0 + 3 * hp0;
            const int d  = WP_ - wp0;
            const float sc0 = scl_s[p0 + 0], sc1 = scl_s[p0 + 1];
            const float sc2 = scl_s[p0 + 2], sc3 = scl_s[p0 + 3];
            const float tt0 = t2_s[p0 + 0], tt1 = t2_s[p0 + 1];
            const float tt2 = t2_s[p0 + 2], tt3 = t2_s[p0 + 3];
            float4 A0, A1, A2, A3, Q0, Q1, Q2, Q3;
            WINDOW10(cs_q[0], b0, d, A0, A1, A2, A3)
            WINDOW10(cs_q[1], b0, d, Q0, Q1, Q2, Q3)
            *reinterpret_cast<float4*>(ob0 + p0) =
                make_float4(A0.x * sc0 - ce0 * tt0, A1.x * sc1 - ce0 * tt1,
                            A2.x * sc2 - ce0 * tt2, A3.x * sc3 - ce0 * tt3);
            *reinterpret_cast<float4*>(ob1 + p0) =
                make_float4(A0.y * sc0 - ce1 * tt0, A1.y * sc1 - ce1 * tt1,
                            A2.y * sc2 - ce1 * tt2, A3.y * sc3 - ce1 * tt3);
            *reinterpret_cast<float4*>(ob2 + p0) =
                make_float4(A0.z * sc0 - ce2 * tt0, A1.z * sc1 - ce2 * tt1,
                            A2.z * sc2 - ce2 * tt2, A3.z * sc3 - ce2 * tt3);
            *reinterpret_cast<float4*>(ob3 + p0) =
                make_float4(A0.w * sc0 - ce3 * tt0, A1.w * sc1 - ce3 * tt1,
                            A2.w * sc2 - ce3 * tt2, A3.w * sc3 - ce3 * tt3);
            *reinterpret_cast<float4*>(ob4 + p0) =
                make_float4(Q0.x * sc0 - ce4 * tt0, Q1.x * sc1 - ce4 * tt1,
                            Q2.x * sc2 - ce4 * tt2, Q3.x * sc3 - ce4 * tt3);
            *reinterpret_cast<float4*>(ob5 + p0) =
                make_float4(Q0.y * sc0 - ce5 * tt0, Q1.y * sc1 - ce5 * tt1,
                            Q2.y * sc2 - ce5 * tt2, Q3.y * sc3 - ce5 * tt3);
            *reinterpret_cast<float4*>(ob6 + p0) =
                make_float4(Q0.z * sc0 - ce6 * tt0, Q1.z * sc1 - ce6 * tt1,
                            Q2.z * sc2 - ce6 * tt2, Q3.z * sc3 - ce6 * tt3);
            *reinterpret_cast<float4*>(ob7 + p0) =
                make_float4(Q0.w * sc0 - ce7 * tt0, Q1.w * sc1 - ce7 * tt1,
                            Q2.w * sc2 - ce7 * tt2, Q3.w * sc3 - ce7 * tt3);
        } else if (t < 252) {                          // 3 scalar stragglers
            const int u = t - 249;
            const int p = (u < m) ? u : 996 + u;       // {0..m-1} ∪ {m+996..998}
            const int hp = p / WP_, wp = p - hp * WP_;
            const int base = hp * W_ + wp;
            const float4 a0 = cs_q[0][(base + 0) & 3][(base + 0) >> 2];
            const float4 a1 = cs_q[0][(base + 1) & 3][(base + 1) >> 2];
            const float4 a2 = cs_q[0][(base + 2) & 3][(base + 2) >> 2];
            const float4 a3 = cs_q[0][(base + 3) & 3][(base + 3) >> 2];
            const float4 q0 = cs_q[1][(base + 0) & 3][(base + 0) >> 2];
            const float4 q1 = cs_q[1][(base + 1) & 3][(base + 1) >> 2];
            const float4 q2 = cs_q[1][(base + 2) & 3][(base + 2) >> 2];
            const float4 q3 = cs_q[1][(base + 3) & 3][(base + 3) >> 2];
            const float sc = scl_s[p], tt = t2_s[p];
            ob0[p] = (a0.x + a1.x + a2.x + a3.x) * sc - ce0 * tt;
            ob1[p] = (a0.y + a1.y + a2.y + a3.y) * sc - ce1 * tt;
            ob2[p] = (a0.z + a1.z + a2.z + a3.z) * sc - ce2 * tt;
            ob3[p] = (a0.w + a1.w + a2.w + a3.w) * sc - ce3 * tt;
            ob4[p] = (q0.x + q1.x + q2.x + q3.x) * sc - ce4 * tt;
            ob5[p] = (q0.y + q1.y + q2.y + q3.y) * sc - ce5 * tt;
            ob6[p] = (q0.z + q1.z + q2.z + q3.z) * sc - ce6 * tt;
            ob7[p] = (q0.w + q1.w + q2.w + q3.w) * sc - ce7 * tt;
        }
    }
}

// ---------------------------------------------------------------------------
extern "C" void kernel_launch(void* const* d_in, const int* in_sizes, int n_in,
                              void* d_out, int out_size, void* d_ws, size_t ws_size,
                              hipStream_t stream)
{
    const float* x      = (const float*)d_in[0];
    const float* conv_w = (const float*)d_in[1];
    const float* cent   = (const float*)d_in[2];
    float* out = (float*)d_out;
    float* ws  = (float*)d_ws;

    // workspace layout (floats); p-indexed buffers use padded stride 1000
    float* xnT  = ws;                       // 614400
    float* xnP  = ws + 614400;              // 614400
    float* sa   = ws + 1228800;             // 307200
    float* vg_u = ws + 1536000;             // 32768
    float* vg_r = ws + 1568768;             // 256
    float* nsqp = ws + 1569024;             // 1024*1000 = 1024000
    float* inv1 = ws + 2593024;             // 256*1000  = 256000
    float* rloc = ws + 2849024;             // 256*1000  = 256000
    float* inv2 = ws + 3105024;             // 4*1000    = 4000

    float* outl = out + (size_t)N_ * KC_;   // output 1 region

    k1_norm_softmax<<<N_ * H_ * 2, 256, 0, stream>>>(x, conv_w, xnT, xnP, sa);
    k4_merged<<<256 + N_ * K_ * 4, 256, 0, stream>>>(sa, xnT, xnP, cent,
                                                     nsqp, vg_u, vg_r);
    k5_merged<<<256 + N_, 256, 0, stream>>>(nsqp, inv1, rloc, vg_u, vg_r, out);
    k6_inv2<<<N_, 256, 0, stream>>>(rloc, inv2);
    k7_write<<<N_ * K_ * 4, 256, 0, stream>>>(sa, xnT, cent, inv1, inv2, outl);
}